// Round 2
// baseline (210.578 us; speedup 1.0000x reference)
//
#include <hip/hip_runtime.h>

#define NV    150000
#define CIN   32
#define COUT  64
#define EPSF  1e-5f
#define NCOPY 16

#define NTHR   256
#define NTILES (NV / 16)            // 9375 exact
#define NBLKF  512                  // 2 blocks/CU * 256 CU = 512 -> all co-resident
#define WAVES_TOT (NBLKF * 4)       // 2048 waves
#define TPW    5                    // tiles per wave: 2048*5 = 10240 >= 9375

// ws layout (bytes):
//   [0, 110592)             ushort wfrag[27*4*64*8]  (B-fragment swizzled)
//   [110592, 118784)        float  gstats[NCOPY*128]
//   [118784, 118788)        unsigned barrier counter
#define WS_WFRAG  0
#define WS_GSTATS 110592
#define WS_BAR    (WS_GSTATS + NCOPY * 128 * 4)

typedef short  bf16x8 __attribute__((ext_vector_type(8)));
typedef float  f32x4  __attribute__((ext_vector_type(4)));

union u4bf { uint4 u; bf16x8 h; };

__device__ __forceinline__ unsigned pack_bf2(float a, float b) {
    union { float f; unsigned u; } ca, cb;
    ca.f = a; cb.f = b;
    const unsigned lo = (ca.u + 0x7FFFu + ((ca.u >> 16) & 1u)) >> 16;
    const unsigned hi = (cb.u + 0x7FFFu + ((cb.u >> 16) & 1u)) & 0xFFFF0000u;
    return lo | hi;
}

__device__ __forceinline__ u4bf pack_row(float4 f0, float4 f1) {
    u4bf r;
    r.u.x = pack_bf2(f0.x, f0.y);
    r.u.y = pack_bf2(f0.z, f0.w);
    r.u.z = pack_bf2(f1.x, f1.y);
    r.u.w = pack_bf2(f1.z, f1.w);
    return r;
}

// ---------------------------------------------------------------------------
// K0: prep — weights->B-fragment-swizzled bf16 (27 blocks) + gstats/bar zero.
// ---------------------------------------------------------------------------
__global__ __launch_bounds__(NTHR) void k_prep(
    const float* __restrict__ weight,
    char*        __restrict__ ws)
{
    const int b = blockIdx.x;
    if (b < 27) {
        const int k    = b;
        const int bb   = threadIdx.x >> 6;       // cout block 0..3
        const int lane = threadIdx.x & 63;
        const int quad = lane >> 4;
        const int lm   = lane & 15;
        // entry holds weight[k][quad*8+j][bb*16+lm], j=0..7
        const float* wsrc = weight + (long)k * CIN * COUT + (quad * 8) * COUT + bb * 16 + lm;
        float f[8];
#pragma unroll
        for (int j = 0; j < 8; ++j) f[j] = wsrc[j * COUT];
        uint4 o;
        o.x = pack_bf2(f[0], f[1]);
        o.y = pack_bf2(f[2], f[3]);
        o.z = pack_bf2(f[4], f[5]);
        o.w = pack_bf2(f[6], f[7]);
        ((uint4*)(ws + WS_WFRAG))[(k * 4 + bb) * 64 + lane] = o;
    } else {
        // zero gstats (2048 f32) + barrier counter (covered by 2304 f32 span)
        float* gs = (float*)(ws + WS_GSTATS);
#pragma unroll
        for (int i = 0; i < 9; ++i) gs[threadIdx.x + i * NTHR] = 0.f;
    }
}

// ---------------------------------------------------------------------------
// sidx loader: 26 taps x 16 voxels = 416 items, 7 chunks of 64
// ---------------------------------------------------------------------------
__device__ __forceinline__ void load_sidx(
    const int* __restrict__ nbr, int v0, bool have, int lane, int sidx[7])
{
#pragma unroll
    for (int it = 0; it < 7; ++it) {
        const int item = lane + it * 64;
        int idx = -1;
        if (have && item < 416) {
            const int kp = item >> 4;
            const int k  = kp + (kp >= 13);
            idx = nbr[(long)k * NV + v0 + (item & 15)];
        }
        sidx[it] = idx;
    }
}

// ---------------------------------------------------------------------------
// K1 (persistent, software grid barrier): conv -> registers (5 tiles/wave)
// + BN partials, barrier, finalize stats, affine+ReLU from regs, f32 out.
// Co-residency: __launch_bounds__(256,2) caps VGPR<=256 -> >=2 blocks/CU ->
// 512 blocks all resident with a regular launch (graph-capture safe).
// ---------------------------------------------------------------------------
__global__ __launch_bounds__(NTHR, 2) void k_fused(
    const float* __restrict__ feat,    // [NV, CIN] f32
    char*        __restrict__ ws,      // wfrag + gstats + bar
    const int*   __restrict__ nbr,     // [27, NV]
    float*       __restrict__ gstats,
    float*       __restrict__ out,     // [NV, COUT] f32
    const float* __restrict__ gamma,
    const float* __restrict__ beta)
{
    const uint4* wf = (const uint4*)(ws + WS_WFRAG);
    unsigned* bar = (unsigned*)(ws + WS_BAR);

    const int tid  = threadIdx.x;
    const int lane = tid & 63;
    const int quad = lane >> 4;
    const int lm   = lane & 15;
    const int wid  = blockIdx.x * 4 + (tid >> 6);   // wave id 0..2047

    f32x4 ssum = {0.f, 0.f, 0.f, 0.f};
    f32x4 qsum = {0.f, 0.f, 0.f, 0.f};
    f32x4 acc[TPW][4];
#pragma unroll
    for (int t = 0; t < TPW; ++t)
#pragma unroll
        for (int b = 0; b < 4; ++b) acc[t][b] = (f32x4){0.f, 0.f, 0.f, 0.f};

    // prologue: sidx for tile t=0
    int sidx[7];
    load_sidx(nbr, wid * 16, wid < NTILES, lane, sidx);

#pragma unroll
    for (int t = 0; t < TPW; ++t) {
        const int tile = wid + t * WAVES_TOT;
        const bool have = (tile < NTILES);
        const int v0 = tile * 16;

        // prefetch next tile's scan indices (overlaps this tile's drain)
        int snxt[7];
        if (t + 1 < TPW) {
            const int tn = wid + (t + 1) * WAVES_TOT;
            load_sidx(nbr, tn * 16, tn < NTILES, lane, snxt);
        }

        if (have) {
            // ---- center tap MFMA (f32 feat row packed inline) ----
            {
                const float4* fp = (const float4*)(feat + (long)(v0 + lm) * CIN + quad * 8);
                const u4bf a0 = pack_row(fp[0], fp[1]);
#pragma unroll
                for (int b = 0; b < 4; ++b) {
                    u4bf w; w.u = wf[(13 * 4 + b) * 64 + lane];
                    acc[t][b] = __builtin_amdgcn_mfma_f32_16x16x32_bf16(a0.h, w.h, acc[t][b], 0, 0, 0);
                }
            }

            // ---- ballots -> wave-uniform 26-bit active-k mask ----
            unsigned int kmask = 0u;
#pragma unroll
            for (int it = 0; it < 7; ++it) {
                const unsigned long long m = __ballot(sidx[it] >= 0);
                kmask |= ((m & 0xFFFFull)         ? 1u : 0u) << (it * 4 + 0);
                kmask |= (((m >> 16) & 0xFFFFull) ? 1u : 0u) << (it * 4 + 1);
                kmask |= (((m >> 32) & 0xFFFFull) ? 1u : 0u) << (it * 4 + 2);
                kmask |= ((m >> 48)               ? 1u : 0u) << (it * 4 + 3);
            }

            // ---- drain: 2 active k's per iteration ----
            while (kmask) {
                const int kpA = __ffs(kmask) - 1;
                kmask &= kmask - 1u;
                int kpB = -1;
                if (kmask) { kpB = __ffs(kmask) - 1; kmask &= kmask - 1u; }
                const int kA = kpA + (kpA >= 13);
                const int kB = (kpB >= 0) ? (kpB + (kpB >= 13)) : kA;

                int rawA, rawB;
                switch (kpA >> 2) {
                    case 0: rawA = sidx[0]; break; case 1: rawA = sidx[1]; break;
                    case 2: rawA = sidx[2]; break; case 3: rawA = sidx[3]; break;
                    case 4: rawA = sidx[4]; break; case 5: rawA = sidx[5]; break;
                    default: rawA = sidx[6]; break;
                }
                const int kpB2 = (kpB >= 0) ? kpB : kpA;
                switch (kpB2 >> 2) {
                    case 0: rawB = sidx[0]; break; case 1: rawB = sidx[1]; break;
                    case 2: rawB = sidx[2]; break; case 3: rawB = sidx[3]; break;
                    case 4: rawB = sidx[4]; break; case 5: rawB = sidx[5]; break;
                    default: rawB = sidx[6]; break;
                }
                const int idxA = __shfl(rawA, ((kpA & 3) << 4) | lm);
                int idxB = __shfl(rawB, ((kpB2 & 3) << 4) | lm);
                if (kpB < 0) idxB = -1;

                const float4* fpA = (const float4*)(feat + (long)(idxA < 0 ? 0 : idxA) * CIN + quad * 8);
                const float4* fpB = (const float4*)(feat + (long)(idxB < 0 ? 0 : idxB) * CIN + quad * 8);
                u4bf aA = pack_row(fpA[0], fpA[1]);
                u4bf aB = pack_row(fpB[0], fpB[1]);
                if (idxA < 0) aA.u = make_uint4(0u, 0u, 0u, 0u);
                if (idxB < 0) aB.u = make_uint4(0u, 0u, 0u, 0u);

#pragma unroll
                for (int b = 0; b < 4; ++b) {
                    u4bf wA, wB;
                    wA.u = wf[(kA * 4 + b) * 64 + lane];
                    wB.u = wf[(kB * 4 + b) * 64 + lane];
                    acc[t][b] = __builtin_amdgcn_mfma_f32_16x16x32_bf16(aA.h, wA.h, acc[t][b], 0, 0, 0);
                    acc[t][b] = __builtin_amdgcn_mfma_f32_16x16x32_bf16(aB.h, wB.h, acc[t][b], 0, 0, 0);
                }
            }

            // ---- BN partials from f32 accumulators ----
#pragma unroll
            for (int b = 0; b < 4; ++b) {
                const float r0 = acc[t][b][0], r1 = acc[t][b][1];
                const float r2 = acc[t][b][2], r3 = acc[t][b][3];
                ssum[b] += r0 + r1 + r2 + r3;
                qsum[b] += r0 * r0 + r1 * r1 + r2 * r2 + r3 * r3;
            }
        }

        // rotate prefetched indices in
        if (t + 1 < TPW) {
#pragma unroll
            for (int it = 0; it < 7; ++it) sidx[it] = snxt[it];
        }
    }

    // ---- butterfly over quads ----
#pragma unroll
    for (int off = 16; off < 64; off <<= 1) {
#pragma unroll
        for (int b = 0; b < 4; ++b) {
            ssum[b] += __shfl_xor(ssum[b], off);
            qsum[b] += __shfl_xor(qsum[b], off);
        }
    }

    __shared__ float ls[4][128];
    const int wv = tid >> 6;
    if (quad == 0) {
#pragma unroll
        for (int b = 0; b < 4; ++b) {
            ls[wv][b * 16 + lm]      = ssum[b];
            ls[wv][64 + b * 16 + lm] = qsum[b];
        }
    }
    __syncthreads();
    if (tid < 128) {
        const float v = ls[0][tid] + ls[1][tid] + ls[2][tid] + ls[3][tid];
        atomicAdd(gstats + (blockIdx.x & (NCOPY - 1)) * 128 + tid, v);
    }
    __syncthreads();

    // ---- software grid barrier (all 512 blocks co-resident) ----
    if (tid == 0) {
        __threadfence();  // release our gstats adds device-wide
        __hip_atomic_fetch_add(bar, 1u, __ATOMIC_ACQ_REL, __HIP_MEMORY_SCOPE_AGENT);
        while (__hip_atomic_load(bar, __ATOMIC_ACQUIRE, __HIP_MEMORY_SCOPE_AGENT) < (unsigned)NBLKF) {
            __builtin_amdgcn_s_sleep(8);
        }
    }
    __syncthreads();

    // ---- finalize stats -> scale/shift in LDS (agent-scope loads) ----
    __shared__ float sscale[COUT];
    __shared__ float sshift[COUT];
    if (tid < COUT) {
        float s = 0.f, q = 0.f;
#pragma unroll
        for (int cp = 0; cp < NCOPY; ++cp) {
            s += __hip_atomic_load(gstats + cp * 128 + tid, __ATOMIC_RELAXED, __HIP_MEMORY_SCOPE_AGENT);
            q += __hip_atomic_load(gstats + cp * 128 + 64 + tid, __ATOMIC_RELAXED, __HIP_MEMORY_SCOPE_AGENT);
        }
        const float inv_n = 1.f / (float)NV;
        const float mean = s * inv_n;
        float var = q * inv_n - mean * mean;
        var = fmaxf(var, 0.f);
        const float rstd = rsqrtf(var + EPSF);
        const float sc = gamma[tid] * rstd;
        sscale[tid] = sc;
        sshift[tid] = beta[tid] - mean * sc;
    }
    __syncthreads();

    float scv[4], shv[4];
#pragma unroll
    for (int b = 0; b < 4; ++b) {
        scv[b] = sscale[b * 16 + lm];
        shv[b] = sshift[b * 16 + lm];
    }

    // ---- affine + ReLU straight from registers -> f32 out ----
#pragma unroll
    for (int t = 0; t < TPW; ++t) {
        const int tile = wid + t * WAVES_TOT;
        if (tile >= NTILES) continue;
        const int v0 = tile * 16;
#pragma unroll
        for (int b = 0; b < 4; ++b) {
#pragma unroll
            for (int r = 0; r < 4; ++r) {
                out[(long)(v0 + quad * 4 + r) * COUT + b * 16 + lm] =
                    fmaxf(acc[t][b][r] * scv[b] + shv[b], 0.f);
            }
        }
    }
}

// ---------------------------------------------------------------------------
extern "C" void kernel_launch(void* const* d_in, const int* in_sizes, int n_in,
                              void* d_out, int out_size, void* d_ws, size_t ws_size,
                              hipStream_t stream) {
    const float* feat   = (const float*)d_in[0];
    const float* weight = (const float*)d_in[1];
    const float* gamma  = (const float*)d_in[2];
    const float* beta   = (const float*)d_in[3];
    const int*   nbr    = (const int*)d_in[4];
    float* out = (float*)d_out;

    char*  ws     = (char*)d_ws;
    float* gstats = (float*)(ws + WS_GSTATS);

    k_prep<<<28, NTHR, 0, stream>>>(weight, ws);
    k_fused<<<NBLKF, NTHR, 0, stream>>>(feat, ws, nbr, gstats, out, gamma, beta);
}